// Round 6
// baseline (1788.094 us; speedup 1.0000x reference)
//
#include <hip/hip_runtime.h>

#define BLOCK 256
#define HROW 72   // LDS h-tile row stride in halves (144 B): 36 words ≡ 4 mod 32 -> 2-way (free)

typedef _Float16 half_t;
typedef __attribute__((ext_vector_type(8))) _Float16 half8;
typedef __attribute__((ext_vector_type(4))) float float4v;

#define L2E  1.4426950408889634f
#define L2E2 2.8853900817779268f

__device__ __forceinline__ float rcp_(float x) { return __builtin_amdgcn_rcpf(x); }
__device__ __forceinline__ float ex2(float x)  { return __builtin_amdgcn_exp2f(x); }

// ---------------- MLP kernel (~90us, near vector roofline; untouched) ----------------
extern "C" __global__ void __launch_bounds__(BLOCK, 1) mlp_kernel(
    const float* __restrict__ inputs,
    const float* __restrict__ mW0, const float* __restrict__ mb0,
    const float* __restrict__ mW1, const float* __restrict__ mb1,
    const float* __restrict__ mW2, const float* __restrict__ mb2,
    const float* __restrict__ pW, const float* __restrict__ pb,
    float* __restrict__ out, int n)
{
    int b = blockIdx.x * BLOCK + threadIdx.x;
    if (b >= n) return;
    float f0 = inputs[(size_t)b * 18 + 16], f1 = inputs[(size_t)b * 18 + 17];
    float h0[64];
    #pragma unroll
    for (int i = 0; i < 64; ++i)
        h0[i] = fmaxf(fmaf(mW0[2 * i], f0, fmaf(mW0[2 * i + 1], f1, mb0[i])), 0.0f);
    float acc2[32];
    #pragma unroll
    for (int j = 0; j < 32; ++j) acc2[j] = mb2[j];
    #pragma unroll 2
    for (int i = 0; i < 64; ++i) {
        float a = mb1[i];
        #pragma unroll
        for (int k = 0; k < 64; ++k) a = fmaf(mW1[i * 64 + k], h0[k], a);
        a = fmaxf(a, 0.0f);
        #pragma unroll
        for (int j = 0; j < 32; ++j) acc2[j] = fmaf(mW2[j * 64 + i], a, acc2[j]);
    }
    float out0 = pb[0], out1 = pb[1];
    #pragma unroll
    for (int j = 0; j < 32; ++j) {
        out0 = fmaf(pW[256 + j], acc2[j], out0);
        out1 = fmaf(pW[288 + 256 + j], acc2[j], out1);
    }
    ((float2*)out)[b] = make_float2(out0, out1);
}

// ---------------- LSTM step ----------------
// Preacts arrive PRE-SCALED by log2e (2*log2e for g). Fused one-rcp cell update:
//   P = (1+Bi)(1+Bg), F = 1+Bf
//   cn = (Bf*P*c + (Bi*Bg - Bi)*F) / (P*F)          [1 rcp instead of 2]
//   hv = (Bo*Cc - Bo) / ((1+Bo)(1+Cc)),  Cc = exp2(cn*2log2e)
template <bool LAST>
__device__ __forceinline__ void lstm_step(
    const float* __restrict__ xt,          // xt + t*64
    const half_t* __restrict__ src, half_t* __restrict__ dst,
    const half8 Bf[4][2], const float wih_v[4], const float bias_v[4],
    int l15, int quad, int jcol,
    float4v cst[4],
    const float* __restrict__ pWz,         // pW + zbase (LAST only)
    float* __restrict__ wpw)               // wp[w] base: [64][2] floats (LAST only)
{
    float ph0, pc0, ph1, pc1;
    if (LAST) {
        ph0 = pWz[jcol];       pc0 = pWz[64 + jcol];
        ph1 = pWz[288 + jcol]; pc1 = pWz[288 + 64 + jcol];
    }
    #pragma unroll
    for (int mt = 0; mt < 4; ++mt) {
        float4v x4 = *(const float4v*)&xt[mt * 16 + quad * 4];
        half8 a0 = *(const half8*)&src[(mt * 16 + l15) * HROW + quad * 8];
        half8 a1 = *(const half8*)&src[(mt * 16 + l15) * HROW + 32 + quad * 8];
        float4v ag[4];
        #pragma unroll
        for (int gg = 0; gg < 4; ++gg) {
            float4v ai;
            #pragma unroll
            for (int reg = 0; reg < 4; ++reg) ai[reg] = fmaf(x4[reg], wih_v[gg], bias_v[gg]);
            ai = __builtin_amdgcn_mfma_f32_16x16x32_f16(a0, Bf[gg][0], ai, 0, 0, 0);
            ai = __builtin_amdgcn_mfma_f32_16x16x32_f16(a1, Bf[gg][1], ai, 0, 0, 0);
            ag[gg] = ai;
        }
        float po0[4], po1[4];
        #pragma unroll
        for (int reg = 0; reg < 4; ++reg) {
            float Bi  = ex2(ag[0][reg]);
            float Bff = ex2(ag[1][reg]);
            float Bg  = ex2(ag[2][reg]);
            float Bo  = ex2(ag[3][reg]);
            float P   = (1.0f + Bi) * (1.0f + Bg);
            float F   = 1.0f + Bff;
            float t2  = fmaf(Bi, Bg, -Bi);                   // Bi*Bg - Bi
            float t1  = Bff * cst[mt][reg] * P;              // Bf*c*P
            float num = fmaf(t2, F, t1);
            float cn  = num * rcp_(P * F);
            cst[mt][reg] = cn;
            float Cc  = ex2(cn * L2E2);
            float hv  = fmaf(Bo, Cc, -Bo) * rcp_((1.0f + Bo) * (1.0f + Cc));
            if (LAST) {
                po0[reg] = fmaf(ph0, hv, pc0 * cn);
                po1[reg] = fmaf(ph1, hv, pc1 * cn);
            } else {
                dst[(mt * 16 + quad * 4 + reg) * HROW + jcol] = (half_t)hv;
            }
        }
        if (LAST) {
            // reduce over the 16 j-lanes sharing each batch row, accumulate into wp
            #pragma unroll
            for (int reg = 0; reg < 4; ++reg) {
                #pragma unroll
                for (int s = 1; s < 16; s <<= 1) {
                    po0[reg] += __shfl_xor(po0[reg], s, 64);
                    po1[reg] += __shfl_xor(po1[reg], s, 64);
                }
            }
            if (l15 == 0) {
                #pragma unroll
                for (int reg = 0; reg < 4; ++reg) {
                    int m = mt * 16 + quad * 4 + reg;
                    wpw[m * 2]     += po0[reg];
                    wpw[m * 2 + 1] += po1[reg];
                }
            }
        }
    }
    __syncthreads();
}

__device__ __forceinline__ void lstm_mfma_one(
    const float* __restrict__ Wih, const float* __restrict__ Whh,
    const float* __restrict__ bih, const float* __restrict__ bhh,
    const float* __restrict__ pW, int zbase,
    const float* __restrict__ xt,            // xt[t*64 + b], t in 0..7
    half_t* __restrict__ hbuf,               // [2][64*HROW]
    int w, int lane,
    float* __restrict__ wpw)                 // wp[w] base
{
    const int l15  = lane & 15;
    const int quad = lane >> 4;
    const int jcol = w * 16 + l15;

    // --- weight fragments, PRE-SCALED by log2e (g-gate by 2*log2e) ---
    const float gscale[4] = {L2E, L2E, L2E2, L2E};
    half8 Bf[4][2];
    float wih_v[4], bias_v[4];
    #pragma unroll
    for (int gg = 0; gg < 4; ++gg) {
        const int nrow = gg * 64 + jcol;
        const float s = gscale[gg];
        #pragma unroll
        for (int kf = 0; kf < 2; ++kf) {
            const float4* p = (const float4*)(Whh + nrow * 64 + kf * 32 + quad * 8);
            float4 w0 = p[0], w1 = p[1];
            Bf[gg][kf] = half8{(half_t)(w0.x * s), (half_t)(w0.y * s), (half_t)(w0.z * s), (half_t)(w0.w * s),
                               (half_t)(w1.x * s), (half_t)(w1.y * s), (half_t)(w1.z * s), (half_t)(w1.w * s)};
        }
        wih_v[gg]  = Wih[nrow] * s;
        bias_v[gg] = (bih[nrow] + bhh[nrow]) * s;
    }

    float4v cst[4];

    // --- t = 0: h = c = 0 -> preacts = x*wih_s + b_s (already log2e-scaled) ---
    #pragma unroll
    for (int mt = 0; mt < 4; ++mt) {
        float4v x4 = *(const float4v*)&xt[mt * 16 + quad * 4];
        #pragma unroll
        for (int reg = 0; reg < 4; ++reg) {
            float Bi = ex2(fmaf(x4[reg], wih_v[0], bias_v[0]));
            float Bg = ex2(fmaf(x4[reg], wih_v[2], bias_v[2]));
            float Bo = ex2(fmaf(x4[reg], wih_v[3], bias_v[3]));
            float cn = fmaf(Bi, Bg, -Bi) * rcp_((1.0f + Bi) * (1.0f + Bg));
            cst[mt][reg] = cn;
            float Cc = ex2(cn * L2E2);
            float hv = fmaf(Bo, Cc, -Bo) * rcp_((1.0f + Bo) * (1.0f + Cc));
            hbuf[(mt * 16 + quad * 4 + reg) * HROW + jcol] = (half_t)hv;  // buf 0
        }
    }
    __syncthreads();

    half_t* b0 = hbuf;
    half_t* b1 = hbuf + 64 * HROW;
    // steps 1..6 as 3 double-buffered pairs, step 7 peeled with projection fold
    #pragma unroll 1
    for (int tt = 1; tt < 7; tt += 2) {
        lstm_step<false>(xt + tt * 64,       b0, b1, Bf, wih_v, bias_v, l15, quad, jcol,
                         cst, pW, wpw);
        lstm_step<false>(xt + (tt + 1) * 64, b1, b0, Bf, wih_v, bias_v, l15, quad, jcol,
                         cst, pW, wpw);
    }
    lstm_step<true>(xt + 7 * 64, b0, b1, Bf, wih_v, bias_v, l15, quad, jcol,
                    cst, pW + zbase, wpw);
}

// (256,3): 12 waves/CU target, combined VGPR budget ~170. Live estimate ~140.
// Spill tripwire: FETCH/WRITE_SIZE must stay at ~42MB/8MB.
extern "C" __global__ void __launch_bounds__(BLOCK, 3) lstm_mfma(
    const float* __restrict__ inputs,
    const float* __restrict__ Wih1, const float* __restrict__ Whh1,
    const float* __restrict__ bih1, const float* __restrict__ bhh1,
    const float* __restrict__ Wih2, const float* __restrict__ Whh2,
    const float* __restrict__ bih2, const float* __restrict__ bhh2,
    const float* __restrict__ pW,
    float* __restrict__ out, int n)
{
    __shared__ half_t hbuf[2 * 64 * HROW];   // 18 KB double-buffered h tile
    __shared__ float  xt_lds[16 * 64];       // x transposed [t][b]
    __shared__ float  wp[4][64][2];          // per-wave projection partials (accumulated)

    const int tid  = threadIdx.x;
    const int w    = tid >> 6;
    const int lane = tid & 63;
    const int base = blockIdx.x * 64;

    // zero wp (4*64*2 = 512 floats) and stage x transposed
    ((float2*)wp)[tid] = make_float2(0.0f, 0.0f);
    for (int idx = tid; idx < 64 * 18; idx += BLOCK) {
        int row = idx / 18, c = idx % 18;
        float v = inputs[(size_t)(base + row) * 18 + c];
        if (c < 16) xt_lds[c * 64 + row] = v;
    }
    __syncthreads();

    float* wpw = &wp[w][0][0];
    lstm_mfma_one(Wih1, Whh1, bih1, bhh1, pW, 0,   xt_lds,          hbuf, w, lane, wpw);
    lstm_mfma_one(Wih2, Whh2, bih2, bhh2, pW, 128, xt_lds + 8 * 64, hbuf, w, lane, wpw);

    // final barrier already executed inside the last lstm_step
    if (tid < 64) {
        int gb = base + tid;
        float2 o = ((float2*)out)[gb];   // MLP kernel ran first on this stream
        o.x += wp[0][tid][0] + wp[1][tid][0] + wp[2][tid][0] + wp[3][tid][0];
        o.y += wp[0][tid][1] + wp[1][tid][1] + wp[2][tid][1] + wp[3][tid][1];
        ((float2*)out)[gb] = o;
    }
}

extern "C" void kernel_launch(void* const* d_in, const int* in_sizes, int n_in,
                              void* d_out, int out_size, void* d_ws, size_t ws_size,
                              hipStream_t stream) {
    const int n = in_sizes[0] / 18;           // 1048576
    mlp_kernel<<<(n + BLOCK - 1) / BLOCK, BLOCK, 0, stream>>>(
        (const float*)d_in[0],
        (const float*)d_in[9],  (const float*)d_in[10],
        (const float*)d_in[11], (const float*)d_in[12],
        (const float*)d_in[13], (const float*)d_in[14],
        (const float*)d_in[15], (const float*)d_in[16],
        (float*)d_out, n);
    lstm_mfma<<<n / 64, BLOCK, 0, stream>>>(
        (const float*)d_in[0],
        (const float*)d_in[1], (const float*)d_in[2],
        (const float*)d_in[3], (const float*)d_in[4],
        (const float*)d_in[5], (const float*)d_in[6],
        (const float*)d_in[7], (const float*)d_in[8],
        (const float*)d_in[15],
        (float*)d_out, n);
}